// Round 9
// baseline (173.298 us; speedup 1.0000x reference)
//
#include <hip/hip_runtime.h>
#include <hip/hip_bf16.h>

#define B_N 32
#define SX 2048
#define SY 512
#define DIM 1024
#define NTOK 2
#define DN 128
#define ODIM 1024
#define BM 64
#define QK 128  // K eighth staged in LDS
#define NQ 8

typedef __bf16 bf16;
typedef __bf16 bf16x8 __attribute__((ext_vector_type(8)));
typedef __bf16 bf16x4 __attribute__((ext_vector_type(4)));
typedef float f32x4 __attribute__((ext_vector_type(4)));

__device__ __forceinline__ f32x4 mfma16(bf16x8 a, bf16x8 b, f32x4 c) {
  return __builtin_amdgcn_mfma_f32_16x16x32_bf16(a, b, c, 0, 0, 0);
}

// Convert weights fp32 -> bf16 once per call (weights are small, L2-resident).
__global__ __launch_bounds__(256) void prep_kernel(const float* __restrict__ Wd,
                                                   const float* __restrict__ Wu,
                                                   bf16* __restrict__ wdb,
                                                   bf16* __restrict__ wub) {
  int i = blockIdx.x * 256 + threadIdx.x;
  if (i < DN * DIM) {
    wdb[i] = (bf16)Wd[i];
    wub[i] = (bf16)Wu[i];
  }
}

// tokens[b,t,:] = latent[t] + sum_s softmax_s(latent[t].y[b,s]) * y[b,s]
// Only needed when gate != 0 (slow path; bench has gate == 0).
__global__ __launch_bounds__(256) void tokens_kernel(const float* __restrict__ y,
                                                     const float* __restrict__ lat,
                                                     const float* __restrict__ gate,
                                                     float* __restrict__ tokens) {
  if (gate[0] == 0.0f) return;
  __shared__ float s_lat[NTOK][DIM];
  __shared__ float s_sc[NTOK][SY];
  int b = blockIdx.x;
  int tid = threadIdx.x, wave = tid >> 6, lane = tid & 63;
  const float* yb = y + (size_t)b * SY * DIM;
  for (int i = tid; i < NTOK * DIM; i += 256) ((float*)s_lat)[i] = lat[i];
  __syncthreads();
  for (int s = wave * 128; s < wave * 128 + 128; ++s) {
    const float* yr = yb + (size_t)s * DIM;
    float d0 = 0.f, d1 = 0.f;
#pragma unroll
    for (int i = 0; i < 4; ++i) {
      f32x4 v = *(const f32x4*)(yr + lane * 4 + i * 256);
      f32x4 l0 = *(const f32x4*)(&s_lat[0][lane * 4 + i * 256]);
      f32x4 l1 = *(const f32x4*)(&s_lat[1][lane * 4 + i * 256]);
      d0 += v[0] * l0[0] + v[1] * l0[1] + v[2] * l0[2] + v[3] * l0[3];
      d1 += v[0] * l1[0] + v[1] * l1[1] + v[2] * l1[2] + v[3] * l1[3];
    }
#pragma unroll
    for (int off = 32; off > 0; off >>= 1) {
      d0 += __shfl_xor(d0, off);
      d1 += __shfl_xor(d1, off);
    }
    if (lane == 0) { s_sc[0][s] = d0; s_sc[1][s] = d1; }
  }
  __syncthreads();
  if (wave < 2) {
    float m = -3.4e38f;
    for (int s = lane; s < SY; s += 64) m = fmaxf(m, s_sc[wave][s]);
#pragma unroll
    for (int off = 32; off > 0; off >>= 1) m = fmaxf(m, __shfl_xor(m, off));
    float sum = 0.f;
    for (int s = lane; s < SY; s += 64) {
      float e = expf(s_sc[wave][s] - m);
      s_sc[wave][s] = e;
      sum += e;
    }
#pragma unroll
    for (int off = 32; off > 0; off >>= 1) sum += __shfl_xor(sum, off);
    float inv = 1.f / sum;
    for (int s = lane; s < SY; s += 64) s_sc[wave][s] *= inv;
  }
  __syncthreads();
  float a0[4] = {0.f, 0.f, 0.f, 0.f}, a1[4] = {0.f, 0.f, 0.f, 0.f};
  for (int s = 0; s < SY; ++s) {
    float p0 = s_sc[0][s], p1 = s_sc[1][s];
    const float* yr = yb + (size_t)s * DIM;
#pragma unroll
    for (int i = 0; i < 4; ++i) {
      float v = yr[tid + i * 256];
      a0[i] += p0 * v;
      a1[i] += p1 * v;
    }
  }
  float* tb = tokens + (size_t)b * NTOK * DIM;
#pragma unroll
  for (int i = 0; i < 4; ++i) {
    tb[tid + i * 256] = s_lat[0][tid + i * 256] + a0[i];
    tb[DIM + tid + i * 256] = s_lat[1][tid + i * 256] + a1[i];
  }
}

// gate != 0 slow path only: xp = x + softmax(x.tok)*tok*gate, into d_out.
__global__ __launch_bounds__(256) void xprime_kernel(const float* __restrict__ x,
                                                     const float* __restrict__ gate,
                                                     const float* __restrict__ tokens,
                                                     float* __restrict__ xp) {
  float g = gate[0];
  if (g == 0.0f) return;
  __shared__ float s_tok[NTOK][DIM];
  __shared__ float s_c[BM][2];
  int tid = threadIdx.x, w = tid >> 6, lane = tid & 63;
  size_t m0 = (size_t)blockIdx.x * BM;
  int b = (int)(m0 / SX);
  const float* xb = x + m0 * DIM;
  const float* tokb = tokens + (size_t)b * NTOK * DIM;
  for (int i = tid; i < NTOK * DIM; i += 256) ((float*)s_tok)[i] = tokb[i];
  __syncthreads();
  for (int i = 0; i < 16; ++i) {
    int r = w * 16 + i;
    const float* xrow = xb + (size_t)r * DIM;
    float d0 = 0.f, d1 = 0.f;
#pragma unroll
    for (int c = 0; c < 4; ++c) {
      f32x4 v = *(const f32x4*)(xrow + lane * 4 + c * 256);
      f32x4 t0 = *(const f32x4*)(&s_tok[0][lane * 4 + c * 256]);
      f32x4 t1 = *(const f32x4*)(&s_tok[1][lane * 4 + c * 256]);
      d0 += v[0] * t0[0] + v[1] * t0[1] + v[2] * t0[2] + v[3] * t0[3];
      d1 += v[0] * t1[0] + v[1] * t1[1] + v[2] * t1[2] + v[3] * t1[3];
    }
#pragma unroll
    for (int off = 32; off > 0; off >>= 1) {
      d0 += __shfl_xor(d0, off);
      d1 += __shfl_xor(d1, off);
    }
    if (lane == 0) {
      float mm = fmaxf(d0, d1);
      float e0 = expf(d0 - mm), e1 = expf(d1 - mm);
      float inv = g / (e0 + e1);
      s_c[r][0] = e0 * inv;
      s_c[r][1] = e1 * inv;
    }
  }
  __syncthreads();
  float* xpb = xp + m0 * DIM;
  for (int r = w * 16; r < w * 16 + 16; ++r) {
    float c0 = s_c[r][0], c1 = s_c[r][1];
#pragma unroll
    for (int c = 0; c < 4; ++c) {
      f32x4 v = *(const f32x4*)(xb + (size_t)r * DIM + lane * 4 + c * 256);
      f32x4 t0 = *(const f32x4*)(&s_tok[0][lane * 4 + c * 256]);
      f32x4 t1 = *(const f32x4*)(&s_tok[1][lane * 4 + c * 256]);
      f32x4 o;
#pragma unroll
      for (int j = 0; j < 4; ++j) o[j] = v[j] + c0 * t0[j] + c1 * t1[j];
      *(f32x4*)(xpb + (size_t)r * DIM + lane * 4 + c * 256) = o;
    }
  }
}

// Phase1 (pure READ streamer): Z = relu(x' Wd^T), Z (bf16, 16KB/block) stored
// into the first 16KB of the block's own out region (read-before-overwrite:
// all x' reads of this block complete before Z store; phase2 re-reads it).
// R8's quarter pipeline with QK=128 -> 32KB LDS -> 4 blocks/CU (32 waves).
__global__ __launch_bounds__(512, 8) void phase1_kernel(const float* __restrict__ x,
                                                        const float* __restrict__ gate,
                                                        const float* __restrict__ xp,
                                                        const bf16* __restrict__ wdb,
                                                        float* __restrict__ outbuf) {
  __shared__ bf16 xq[2][BM * QK];  // 2 x 16 KB, XOR-swizzled

  int tid = threadIdx.x, w = tid >> 6, lane = tid & 63;
  int lq = lane >> 4, lr = lane & 15;
  size_t m0 = (size_t)blockIdx.x * BM;
  float g = gate[0];
  const float* xb = ((g != 0.f) ? xp : x) + m0 * DIM;

  // staging map: row = tid>>3 (64 rows), float col = (tid&7)*16 (64 B/thread)
  int srow = tid >> 3;
  int scolb = (tid & 7) * 32;  // bf16 byte offset of thread's 16-elem chunk
  const float* xgp = xb + (size_t)srow * DIM + (tid & 7) * 16;

  f32x4 xs[4];     // 16 VGPR staging
  bf16x8 wdr[4];   // 16 VGPR Wd eighth-slice
  f32x4 acc[4] = {};

  const bf16* wdp = wdb + (size_t)(w * 16 + lr) * DIM + lq * 8;
  char* xls = (char*)xq;

  auto XLOAD = [&](int q) {
#pragma unroll
    for (int i = 0; i < 4; ++i) xs[i] = *(const f32x4*)(xgp + q * QK + i * 4);
  };
  auto WLOAD = [&](int q) {
#pragma unroll
    for (int kc = 0; kc < 4; ++kc) wdr[kc] = *(const bf16x8*)(wdp + q * QK + kc * 32);
  };
  auto XWRITE = [&](int buf) {
    char* base = xls + buf * (BM * QK * 2);
    bf16x8 o0, o1;
#pragma unroll
    for (int j = 0; j < 4; ++j) {
      o0[j] = (bf16)xs[0][j];
      o0[4 + j] = (bf16)xs[1][j];
      o1[j] = (bf16)xs[2][j];
      o1[4 + j] = (bf16)xs[3][j];
    }
    int sw = (srow & 7) << 4;
    *(bf16x8*)(base + srow * (QK * 2) + (scolb ^ sw)) = o0;
    *(bf16x8*)(base + srow * (QK * 2) + ((scolb + 16) ^ sw)) = o1;
  };
  auto COMP = [&](int buf) {
    const char* base = xls + buf * (BM * QK * 2);
#pragma unroll
    for (int kc = 0; kc < 4; ++kc) {
#pragma unroll
      for (int mt = 0; mt < 4; ++mt) {
        int row = mt * 16 + lr;
        bf16x8 xf = *(const bf16x8*)(base + row * (QK * 2) +
                                     ((kc * 64 + lq * 16) ^ ((row & 7) << 4)));
        acc[mt] = mfma16(wdr[kc], xf, acc[mt]);  // D[dn-slice][xrow]
      }
    }
  };

  XLOAD(0);
  WLOAD(0);
  XWRITE(0);  // waits x loads; wd still in flight
  __syncthreads();

#pragma unroll
  for (int q = 0; q < NQ; ++q) {
    if (q + 1 < NQ) XLOAD(q + 1);  // in flight across COMP + barrier
    COMP(q & 1);                   // LDS + regs only
    if (q + 1 < NQ) WLOAD(q + 1);
    __syncthreads();
    if (q + 1 < NQ) XWRITE((q + 1) & 1);  // vmcnt drain after compute
    __syncthreads();
  }

  // ReLU -> bf16 Z, plain [row][dn] layout, into block's own out region.
  // Safe: all of this block's x'/x reads completed before the last barrier.
  bf16* zgb = (bf16*)((char*)outbuf + (size_t)blockIdx.x * (BM * ODIM * 4));
#pragma unroll
  for (int mt = 0; mt < 4; ++mt) {
    int xr = mt * 16 + lr;
    bf16x4 pk;
#pragma unroll
    for (int r = 0; r < 4; ++r) pk[r] = (bf16)fmaxf(acc[mt][r], 0.f);
    *(bf16x4*)(zgb + xr * DN + w * 16 + lq * 4) = pk;
  }
}

// Phase2 (pure WRITE streamer): out = Z Wu^T. Z (16KB) read from the block's
// own out region (L2/L3-hot, L1-absorbed across the 8 waves), one barrier
// (Z region is overwritten by rows 0-3 stores), then MFMA + packed stores.
__global__ __launch_bounds__(512, 4) void phase2_kernel(const bf16* __restrict__ wub,
                                                        float* __restrict__ out) {
  int tid = threadIdx.x, w = tid >> 6, lane = tid & 63;
  int lq = lane >> 4, lr = lane & 15;
  size_t m0 = (size_t)blockIdx.x * BM;
  const bf16* zgb = (const bf16*)((const char*)out + (size_t)blockIdx.x * (BM * ODIM * 4));

  bf16x8 zF[4][4];  // [kt][mt]
#pragma unroll
  for (int mt = 0; mt < 4; ++mt)
#pragma unroll
    for (int kt = 0; kt < 4; ++kt)
      zF[kt][mt] = *(const bf16x8*)(zgb + (size_t)(mt * 16 + lr) * DN + kt * 32 + lq * 8);

  __syncthreads();  // all waves' Z loads landed (vmcnt drained) before stores

  float* ob = out + m0 * ODIM;
#pragma unroll 2
  for (int oc16 = 0; oc16 < 8; ++oc16) {
    int base = w * 128 + oc16 * 16;  // wave w owns out cols [w*128, +128)
    bf16x8 wu[4];
#pragma unroll
    for (int kt = 0; kt < 4; ++kt)
      wu[kt] = *(const bf16x8*)(wub + (size_t)(base + lr) * DN + kt * 32 + lq * 8);
    f32x4 a2[4] = {};
#pragma unroll
    for (int kt = 0; kt < 4; ++kt)
#pragma unroll
      for (int mt = 0; mt < 4; ++mt)
        a2[mt] = mfma16(wu[kt], zF[kt][mt], a2[mt]);
#pragma unroll
    for (int mt = 0; mt < 4; ++mt)
      *(f32x4*)(ob + (size_t)(mt * 16 + lr) * ODIM + base + lq * 4) = a2[mt];
  }
}

extern "C" void kernel_launch(void* const* d_in, const int* in_sizes, int n_in,
                              void* d_out, int out_size, void* d_ws, size_t ws_size,
                              hipStream_t stream) {
  const float* x = (const float*)d_in[0];
  const float* y = (const float*)d_in[1];
  const float* lat = (const float*)d_in[2];
  const float* gate = (const float*)d_in[3];
  const float* Wd = (const float*)d_in[4];
  const float* Wu = (const float*)d_in[5];
  float* out = (float*)d_out;
  char* ws = (char*)d_ws;

  float* tokens = (float*)ws;              // 32*2*1024*4   = 262144 B
  bf16* wdb = (bf16*)(ws + 262144);        // 128*1024*2    = 262144 B
  bf16* wub = (bf16*)(ws + 524288);        // 1024*128*2    = 262144 B

  prep_kernel<<<(DN * DIM + 255) / 256, 256, 0, stream>>>(Wd, Wu, wdb, wub);
  tokens_kernel<<<B_N, 256, 0, stream>>>(y, lat, gate, tokens);
  // gate!=0 only: writes x' into d_out; phase1 reads it back per block before
  // overwriting that block's region with Z.
  xprime_kernel<<<(B_N * SX) / BM, 256, 0, stream>>>(x, gate, tokens, out);
  phase1_kernel<<<(B_N * SX) / BM, 512, 0, stream>>>(x, gate, out, wdb, out);
  phase2_kernel<<<(B_N * SX) / BM, 512, 0, stream>>>(wub, out);
}

// Round 10
// 146.046 us; speedup vs baseline: 1.1866x; 1.1866x over previous
//
#include <hip/hip_runtime.h>
#include <hip/hip_bf16.h>

#define B_N 32
#define SX 2048
#define SY 512
#define DIM 1024
#define NTOK 2
#define DN 128
#define ODIM 1024
#define BM 64
#define BK 64
#define NT 16   // K tiles
#define RING 3

typedef __bf16 bf16;
typedef __bf16 bf16x8 __attribute__((ext_vector_type(8)));
typedef __bf16 bf16x4 __attribute__((ext_vector_type(4)));
typedef float f32x4 __attribute__((ext_vector_type(4)));

typedef __attribute__((address_space(3))) unsigned char lds_u8;
typedef const __attribute__((address_space(1))) unsigned char glb_u8;

__device__ __forceinline__ f32x4 mfma16(bf16x8 a, bf16x8 b, f32x4 c) {
  return __builtin_amdgcn_mfma_f32_16x16x32_bf16(a, b, c, 0, 0, 0);
}
__device__ __forceinline__ void gll16(const void* g, void* l) {
  __builtin_amdgcn_global_load_lds((glb_u8*)g, (lds_u8*)l, 16, 0, 0);
}

// Convert weights fp32 -> bf16 once per call.
__global__ __launch_bounds__(256) void prep_kernel(const float* __restrict__ Wd,
                                                   const float* __restrict__ Wu,
                                                   bf16* __restrict__ wdb,
                                                   bf16* __restrict__ wub) {
  int i = blockIdx.x * 256 + threadIdx.x;
  if (i < DN * DIM) {
    wdb[i] = (bf16)Wd[i];
    wub[i] = (bf16)Wu[i];
  }
}

// tokens kernel: only needed when gate != 0 (bench has gate == 0).
__global__ __launch_bounds__(256) void tokens_kernel(const float* __restrict__ y,
                                                     const float* __restrict__ lat,
                                                     const float* __restrict__ gate,
                                                     float* __restrict__ tokens) {
  if (gate[0] == 0.0f) return;
  __shared__ float s_lat[NTOK][DIM];
  __shared__ float s_sc[NTOK][SY];
  int b = blockIdx.x;
  int tid = threadIdx.x, wave = tid >> 6, lane = tid & 63;
  const float* yb = y + (size_t)b * SY * DIM;
  for (int i = tid; i < NTOK * DIM; i += 256) ((float*)s_lat)[i] = lat[i];
  __syncthreads();
  for (int s = wave * 128; s < wave * 128 + 128; ++s) {
    const float* yr = yb + (size_t)s * DIM;
    float d0 = 0.f, d1 = 0.f;
#pragma unroll
    for (int i = 0; i < 4; ++i) {
      f32x4 v = *(const f32x4*)(yr + lane * 4 + i * 256);
      f32x4 l0 = *(const f32x4*)(&s_lat[0][lane * 4 + i * 256]);
      f32x4 l1 = *(const f32x4*)(&s_lat[1][lane * 4 + i * 256]);
      d0 += v[0] * l0[0] + v[1] * l0[1] + v[2] * l0[2] + v[3] * l0[3];
      d1 += v[0] * l1[0] + v[1] * l1[1] + v[2] * l1[2] + v[3] * l1[3];
    }
#pragma unroll
    for (int off = 32; off > 0; off >>= 1) {
      d0 += __shfl_xor(d0, off);
      d1 += __shfl_xor(d1, off);
    }
    if (lane == 0) { s_sc[0][s] = d0; s_sc[1][s] = d1; }
  }
  __syncthreads();
  if (wave < 2) {
    float m = -3.4e38f;
    for (int s = lane; s < SY; s += 64) m = fmaxf(m, s_sc[wave][s]);
#pragma unroll
    for (int off = 32; off > 0; off >>= 1) m = fmaxf(m, __shfl_xor(m, off));
    float sum = 0.f;
    for (int s = lane; s < SY; s += 64) {
      float e = expf(s_sc[wave][s] - m);
      s_sc[wave][s] = e;
      sum += e;
    }
#pragma unroll
    for (int off = 32; off > 0; off >>= 1) sum += __shfl_xor(sum, off);
    float inv = 1.f / sum;
    for (int s = lane; s < SY; s += 64) s_sc[wave][s] *= inv;
  }
  __syncthreads();
  float a0[4] = {0.f, 0.f, 0.f, 0.f}, a1[4] = {0.f, 0.f, 0.f, 0.f};
  for (int s = 0; s < SY; ++s) {
    float p0 = s_sc[0][s], p1 = s_sc[1][s];
    const float* yr = yb + (size_t)s * DIM;
#pragma unroll
    for (int i = 0; i < 4; ++i) {
      float v = yr[tid + i * 256];
      a0[i] += p0 * v;
      a1[i] += p1 * v;
    }
  }
  float* tb = tokens + (size_t)b * NTOK * DIM;
#pragma unroll
  for (int i = 0; i < 4; ++i) {
    tb[tid + i * 256] = s_lat[0][tid + i * 256] + a0[i];
    tb[DIM + tid + i * 256] = s_lat[1][tid + i * 256] + a1[i];
  }
}

// gate != 0 slow path only: xp = x + softmax(x.tok)*tok*gate, into d_out.
__global__ __launch_bounds__(256) void xprime_kernel(const float* __restrict__ x,
                                                     const float* __restrict__ gate,
                                                     const float* __restrict__ tokens,
                                                     float* __restrict__ xp) {
  float g = gate[0];
  if (g == 0.0f) return;
  __shared__ float s_tok[NTOK][DIM];
  __shared__ float s_c[BM][2];
  int tid = threadIdx.x, w = tid >> 6, lane = tid & 63;
  size_t m0 = (size_t)blockIdx.x * BM;
  int b = (int)(m0 / SX);
  const float* xb = x + m0 * DIM;
  const float* tokb = tokens + (size_t)b * NTOK * DIM;
  for (int i = tid; i < NTOK * DIM; i += 256) ((float*)s_tok)[i] = tokb[i];
  __syncthreads();
  for (int i = 0; i < 16; ++i) {
    int r = w * 16 + i;
    const float* xrow = xb + (size_t)r * DIM;
    float d0 = 0.f, d1 = 0.f;
#pragma unroll
    for (int c = 0; c < 4; ++c) {
      f32x4 v = *(const f32x4*)(xrow + lane * 4 + c * 256);
      f32x4 t0 = *(const f32x4*)(&s_tok[0][lane * 4 + c * 256]);
      f32x4 t1 = *(const f32x4*)(&s_tok[1][lane * 4 + c * 256]);
      d0 += v[0] * t0[0] + v[1] * t0[1] + v[2] * t0[2] + v[3] * t0[3];
      d1 += v[0] * t1[0] + v[1] * t1[1] + v[2] * t1[2] + v[3] * t1[3];
    }
#pragma unroll
    for (int off = 32; off > 0; off >>= 1) {
      d0 += __shfl_xor(d0, off);
      d1 += __shfl_xor(d1, off);
    }
    if (lane == 0) {
      float mm = fmaxf(d0, d1);
      float e0 = expf(d0 - mm), e1 = expf(d1 - mm);
      float inv = g / (e0 + e1);
      s_c[r][0] = e0 * inv;
      s_c[r][1] = e1 * inv;
    }
  }
  __syncthreads();
  float* xpb = xp + m0 * DIM;
  for (int r = w * 16; r < w * 16 + 16; ++r) {
    float c0 = s_c[r][0], c1 = s_c[r][1];
#pragma unroll
    for (int c = 0; c < 4; ++c) {
      f32x4 v = *(const f32x4*)(xb + (size_t)r * DIM + lane * 4 + c * 256);
      f32x4 t0 = *(const f32x4*)(&s_tok[0][lane * 4 + c * 256]);
      f32x4 t1 = *(const f32x4*)(&s_tok[1][lane * 4 + c * 256]);
      f32x4 o;
#pragma unroll
      for (int j = 0; j < 4; ++j) o[j] = v[j] + c0 * t0[j] + c1 * t1[j];
      *(f32x4*)(xpb + (size_t)r * DIM + lane * 4 + c * 256) = o;
    }
  }
}

// Fused bottleneck with global_load_lds RING pipeline + counted vmcnt.
// 8 waves, BM=64. Ring of 3 {x fp32 16KB + Wd bf16 16KB} tiles; 4 gll/wave
// per tile; steady state 8 gll (8KB/wave, 64KB/CU) stay IN FLIGHT across
// barriers (s_waitcnt vmcnt(8), never 0 until drain). Pre-swizzled gll
// sources + XOR-swizzled LDS reads (involution, rule #21). cvt f32->bf16
// at fragment-read time. Epilogue: Z via LDS, swapped GEMM2, packed stores.
__global__ __launch_bounds__(512) void main_kernel(const float* __restrict__ x,
                                                   const float* __restrict__ gate,
                                                   const float* __restrict__ xp,
                                                   const bf16* __restrict__ wdb,
                                                   const bf16* __restrict__ wub,
                                                   float* __restrict__ out) {
  // [0,49152): x ring (3 x 16KB fp32 64x64)
  // [49152,98304): wd ring (3 x 16KB bf16 128x64)
  // [98304,114688): Z tile (bf16 64x128)
  __shared__ __align__(16) char smem[114688];

  int tid = threadIdx.x, w = tid >> 6, l = tid & 63;
  int lq = l >> 4, lr = l & 15;
  size_t m0 = (size_t)blockIdx.x * BM;
  float g = gate[0];
  const float* xb = ((g != 0.f) ? xp : x) + m0 * DIM;

  // ---- pre-swizzled gll source pointers (per lane) ----
  const char* xsrc[2];
  const char* wsrc[2];
#pragma unroll
  for (int j = 0; j < 2; ++j) {
    int xr = w * 8 + j * 4 + (l >> 4);                      // x row staged
    int xcb = ((l & 15) * 16) ^ ((j * 4 + (l >> 4)) << 5);  // pre-swizzled byte
    xsrc[j] = (const char*)xb + (size_t)xr * (DIM * 4) + xcb;
    int wr_ = w * 16 + j * 8 + (l >> 3);                    // wd row staged
    int wcb = ((l & 7) * 16) ^ ((l >> 3) << 4);
    wsrc[j] = (const char*)wdb + (size_t)wr_ * (DIM * 2) + wcb;
  }

  f32x4 acc[4] = {};

  auto STAGE = [&](int t) {
    int b = t % RING;
#pragma unroll
    for (int j = 0; j < 2; ++j)
      gll16(xsrc[j] + (size_t)t * (BK * 4),
            smem + b * 16384 + (w * 8 + j * 4) * 256);
#pragma unroll
    for (int j = 0; j < 2; ++j)
      gll16(wsrc[j] + (size_t)t * (BK * 2),
            smem + 49152 + b * 16384 + (w * 16 + j * 8) * 128);
  };

  auto COMP = [&](int b) {
    const char* xt = smem + b * 16384;
    const char* wt = smem + 49152 + b * 16384;
#pragma unroll
    for (int kc = 0; kc < 2; ++kc) {
      int dn = w * 16 + lr;
      bf16x8 wdf = *(const bf16x8*)(wt + dn * 128 +
                                    ((kc * 64 + lq * 16) ^ ((lr & 7) << 4)));
#pragma unroll
      for (int mt = 0; mt < 4; ++mt) {
        int row = mt * 16 + lr;
        int sz = (row & 7) << 5;
        int kb = kc * 128 + lq * 32;
        f32x4 a0 = *(const f32x4*)(xt + row * 256 + (kb ^ sz));
        f32x4 a1 = *(const f32x4*)(xt + row * 256 + ((kb + 16) ^ sz));
        bf16x8 xf;
#pragma unroll
        for (int jj = 0; jj < 4; ++jj) {
          xf[jj] = (bf16)a0[jj];
          xf[4 + jj] = (bf16)a1[jj];
        }
        acc[mt] = mfma16(wdf, xf, acc[mt]);  // D[dn-slice][xrow]
      }
    }
  };

  // ---- prologue: fill the ring ----
  STAGE(0);
  STAGE(1);
  STAGE(2);

#pragma unroll
  for (int t = 0; t < NT; ++t) {
    if (t > 0 && t + 2 < NT) STAGE(t + 2);  // freed by prev iter's end barrier
    if (t + 2 < NT) {
      asm volatile("s_waitcnt vmcnt(8)" ::: "memory");
    } else if (t == NT - 2) {
      asm volatile("s_waitcnt vmcnt(4)" ::: "memory");
    } else {
      asm volatile("s_waitcnt vmcnt(0)" ::: "memory");
    }
    __builtin_amdgcn_sched_barrier(0);
    __builtin_amdgcn_s_barrier();      // tile t in LDS for ALL waves
    COMP(t % RING);
    __builtin_amdgcn_sched_barrier(0); // pin reads before release barrier
    __builtin_amdgcn_s_barrier();      // all waves done reading tile t
  }

  // ---- ReLU -> bf16 Z into swizzled LDS ----
  char* zls = smem + 98304;
#pragma unroll
  for (int mt = 0; mt < 4; ++mt) {
    int xr = mt * 16 + lr;
    int dn = w * 16 + lq * 4;
    bf16x4 pk;
#pragma unroll
    for (int r = 0; r < 4; ++r) pk[r] = (bf16)fmaxf(acc[mt][r], 0.f);
    *(bf16x4*)(zls + xr * (DN * 2) + ((dn * 2) ^ ((xr & 7) << 4))) = pk;
  }
  __syncthreads();

  // ---- GEMM2: out^T-frag = mfma(Wu, Z); packed f32x4 stores ----
  bf16x8 zF[4][4];  // [kt][mt]
#pragma unroll
  for (int mt = 0; mt < 4; ++mt)
#pragma unroll
    for (int kt = 0; kt < 4; ++kt) {
      int xr = mt * 16 + lr;
      zF[kt][mt] = *(const bf16x8*)(zls + xr * (DN * 2) +
                                    (((kt * 32 + lq * 8) * 2) ^ ((xr & 7) << 4)));
    }

  float* ob = out + m0 * ODIM;
#pragma unroll 2
  for (int oc16 = 0; oc16 < 8; ++oc16) {
    int base = w * 128 + oc16 * 16;  // wave w owns out cols [w*128, +128)
    bf16x8 wu[4];
#pragma unroll
    for (int kt = 0; kt < 4; ++kt)
      wu[kt] = *(const bf16x8*)(wub + (size_t)(base + lr) * DN + kt * 32 + lq * 8);
    f32x4 a2[4] = {};
#pragma unroll
    for (int kt = 0; kt < 4; ++kt)
#pragma unroll
      for (int mt = 0; mt < 4; ++mt)
        a2[mt] = mfma16(wu[kt], zF[kt][mt], a2[mt]);
#pragma unroll
    for (int mt = 0; mt < 4; ++mt)
      *(f32x4*)(ob + (size_t)(mt * 16 + lr) * ODIM + base + lq * 4) = a2[mt];
  }
}

extern "C" void kernel_launch(void* const* d_in, const int* in_sizes, int n_in,
                              void* d_out, int out_size, void* d_ws, size_t ws_size,
                              hipStream_t stream) {
  const float* x = (const float*)d_in[0];
  const float* y = (const float*)d_in[1];
  const float* lat = (const float*)d_in[2];
  const float* gate = (const float*)d_in[3];
  const float* Wd = (const float*)d_in[4];
  const float* Wu = (const float*)d_in[5];
  float* out = (float*)d_out;
  char* ws = (char*)d_ws;

  float* tokens = (float*)ws;              // 262144 B
  bf16* wdb = (bf16*)(ws + 262144);        // 262144 B
  bf16* wub = (bf16*)(ws + 524288);        // 262144 B

  prep_kernel<<<(DN * DIM + 255) / 256, 256, 0, stream>>>(Wd, Wu, wdb, wub);
  tokens_kernel<<<B_N, 256, 0, stream>>>(y, lat, gate, tokens);
  // gate!=0 only: writes x' into d_out; main reads it back per block before
  // overwriting that block's region with out.
  xprime_kernel<<<(B_N * SX) / BM, 256, 0, stream>>>(x, gate, tokens, out);
  main_kernel<<<(B_N * SX) / BM, 512, 0, stream>>>(x, gate, out, wdb, wub, out);
}